// Round 5
// baseline (263.606 us; speedup 1.0000x reference)
//
#include <hip/hip_runtime.h>
#include <hip/hip_bf16.h>
#include <hip/hip_fp16.h>

#define GG 8
#define GPP 16
#define AA 65
#define HH 128
#define CC 128
#define NN 2
#define WW 128
#define BB 256
#define EDC_ 10
#define OFF_ 2

typedef __attribute__((ext_vector_type(8))) short bf16x8;
typedef __attribute__((ext_vector_type(4))) float f32x4;
#define MFMA16(a, b, c) __builtin_amdgcn_mfma_f32_16x16x32_bf16(a, b, c, 0, 0, 0)

__device__ __forceinline__ void rz_taps(int o, float scale, int in_size,
                                        int& ia, int& ib, float& f) {
  float pos = (o + 0.5f) * scale - 0.5f;
  float fl = floorf(pos);
  int i0 = (int)fl;
  f = pos - fl;
  ia = i0 < 0 ? 0 : i0;
  int i1 = i0 + 1;
  ib = i1 > (in_size - 1) ? (in_size - 1) : i1;
}

// Compile-time 128->65 tap: pos = (j+0.5)*65/128-0.5 = (130j-63)/256 exactly.
#define JTAP(jc, ja, jb, fj) \
  const int num_ = 130 * (jc) - 63;               \
  const int fl_ = num_ >> 8;                      \
  const int ja = fl_ < 0 ? 0 : fl_;               \
  const int jb = (fl_ + 1 > 64) ? 64 : (fl_ + 1); \
  const float fj = (float)(num_ - (fl_ << 8)) * 0.00390625f;

__device__ __forceinline__ float gelu_exact(float v) {
  return 0.5f * v * (1.0f + erff(v * 0.70710678118654752f));
}

__device__ __forceinline__ short f2b(float f) {
  __hip_bfloat16 h = __float2bfloat16(f);
  return *reinterpret_cast<short*>(&h);
}

#define RSBN 0.99999500003749977f  // 1/sqrt(1+1e-5)

// ---------- W: pre-convert weights to bf16 ----------
__global__ void k_wbf(const float* __restrict__ wq, const float* __restrict__ w1,
                      const float* __restrict__ w2, short* __restrict__ wqb,
                      short* __restrict__ w1b, short* __restrict__ w2b) {
  int i = blockIdx.x * 256 + threadIdx.x;
  if (i < 32768) wqb[i] = f2b(wq[i]);
  if (i < 65536) { w1b[i] = f2b(w1[i]); w2b[i] = f2b(w2[i]); }
}

// ---------- A: base_relative (32,255,255) -> relA (32,65,65) + padded q/k copies ----------
__global__ void k_relA(const float* __restrict__ base, float* __restrict__ relA,
                       float* __restrict__ relAp, float* __restrict__ relATp) {
  int idx = blockIdx.x * 256 + threadIdx.x;
  if (idx >= 32 * AA * AA) return;
  int j = idx % AA;
  int r = idx / AA;
  int i = r % AA;
  int c = r / AA;
  int ia, ib, ja, jb; float fi, fj;
  rz_taps(i, 255.0f / 65.0f, 255, ia, ib, fi);
  rz_taps(j, 255.0f / 65.0f, 255, ja, jb, fj);
  const float* S = base + (size_t)c * 255 * 255;
  float v = (1.0f - fi) * ((1.0f - fj) * S[ia * 255 + ja] + fj * S[ia * 255 + jb])
          + fi * ((1.0f - fj) * S[ib * 255 + ja] + fj * S[ib * 255 + jb]);
  relA[idx] = v;
  if (c < 8) relAp[c * 4420 + i * 68 + j] = v;
  else if (c < 16) relATp[(c - 8) * 4420 + j * 68 + i] = v;
}

// ---------- B: veI[c][a][i] = i-upsampled (65->128) v_emb on the 65-j grid ----------
__global__ void k_vei(const float* __restrict__ relA, float* __restrict__ veI) {
  int idx = blockIdx.x * 256 + threadIdx.x;
  if (idx >= 16 * AA * 128) return;
  int i = idx & 127;
  int r = idx >> 7;
  int a = r % AA, c = r / AA;
  int ia, ib; float fi;
  rz_taps(i, 65.0f / 128.0f, 65, ia, ib, fi);
  const float* S = relA + (size_t)(16 + c) * (AA * AA);
  veI[idx] = (1.0f - fi) * S[ia * AA + a] + fi * S[ib * AA + a];
}

// ---------- MFMA GEMM 1: qkv = BN(Wqkv . x); ob fastest for X L2 reuse ----------
__global__ __launch_bounds__(256) void k_qkv_mfma(
    const float* __restrict__ x, const short* __restrict__ wqb,
    const float* __restrict__ bg, const float* __restrict__ bb,
    float* __restrict__ out) {
  const int ob = blockIdx.x * 128;
  const int pb = blockIdx.y * 128;
  const int n = blockIdx.z;
  __shared__ short Asm[128 * 40];
  __shared__ short Bsm[128 * 40];
  const int t = threadIdx.x;
  const int lane = t & 63, wv = t >> 6;
  const int wm = wv >> 1, wn = wv & 1;
  const int lr = lane & 15, lk = (lane >> 4) * 8;
  f32x4 acc[4][4];
  #pragma unroll
  for (int a = 0; a < 4; ++a)
    #pragma unroll
    for (int b = 0; b < 4; ++b)
      #pragma unroll
      for (int q = 0; q < 4; ++q) acc[a][b][q] = 0.f;
  const float* X = x + (size_t)n * 128 * 16384;
  for (int k0 = 0; k0 < 128; k0 += 32) {
    #pragma unroll
    for (int i2 = 0; i2 < 2; ++i2) {
      int u = t + 256 * i2;
      int row = u >> 2, kq = (u & 3) * 8;
      *(bf16x8*)&Asm[row * 40 + kq] = *(const bf16x8*)&wqb[(ob + row) * 128 + k0 + kq];
    }
    #pragma unroll
    for (int i4 = 0; i4 < 4; ++i4) {
      int u = t + 256 * i4;
      int k = u >> 5, p4 = (u & 31) * 4;
      float4 xv = *(const float4*)&X[(size_t)(k0 + k) * 16384 + pb + p4];
      Bsm[(p4 + 0) * 40 + k] = f2b(xv.x);
      Bsm[(p4 + 1) * 40 + k] = f2b(xv.y);
      Bsm[(p4 + 2) * 40 + k] = f2b(xv.z);
      Bsm[(p4 + 3) * 40 + k] = f2b(xv.w);
    }
    __syncthreads();
    bf16x8 af[4], bfr[4];
    #pragma unroll
    for (int mf = 0; mf < 4; ++mf) af[mf] = *(bf16x8*)&Asm[(wm * 64 + mf * 16 + lr) * 40 + lk];
    #pragma unroll
    for (int nf = 0; nf < 4; ++nf) bfr[nf] = *(bf16x8*)&Bsm[(wn * 64 + nf * 16 + lr) * 40 + lk];
    #pragma unroll
    for (int mf = 0; mf < 4; ++mf)
      #pragma unroll
      for (int nf = 0; nf < 4; ++nf)
        acc[mf][nf] = MFMA16(af[mf], bfr[nf], acc[mf][nf]);
    __syncthreads();
  }
  #pragma unroll
  for (int mf = 0; mf < 4; ++mf) {
    #pragma unroll
    for (int r = 0; r < 4; ++r) {
      int o = ob + wm * 64 + mf * 16 + (lane >> 4) * 4 + r;
      float sc = bg[o] * RSBN, sh = bb[o];
      #pragma unroll
      for (int nf = 0; nf < 4; ++nf) {
        int p = pb + wn * 64 + nf * 16 + lr;
        out[((size_t)(n * 256 + o)) * 16384 + p] = acc[mf][nf][r] * sc + sh;
      }
    }
  }
}

// ---------- D: downsample qkv along i (128->65), split ----------
__global__ void k_down(const float* __restrict__ qkv, float* __restrict__ qa,
                       float* __restrict__ ka, float* __restrict__ va) {
  int idx = blockIdx.x * 256 + threadIdx.x;
  if (idx >= BB * GG * 32 * AA) return;
  int w = idx & 127;
  int r = idx >> 7;
  int a = r % AA; r /= AA;
  int cc = r & 31; r >>= 5;
  int g = r & 7;
  int n = r >> 3;
  int o = g * 32 + cc;
  int ia, ib; float f;
  rz_taps(a, 128.0f / 65.0f, 128, ia, ib, f);
  const float* src = qkv + ((size_t)(n * 256 + o)) * 16384 + w;
  float v = (1.0f - f) * src[ia * 128] + f * src[ib * 128];
  int bg = (n * 128 + w) * 8 + g;
  if (cc < 8)       qa[((size_t)bg * 8 + cc) * AA + a] = v;
  else if (cc < 16) ka[((size_t)bg * 8 + (cc - 8)) * AA + a] = v;
  else              va[((size_t)bg * 16 + (cc - 16)) * AA + a] = v;
}

// ---------- F: fused sim + softmax(register-T fold) + sv/sve + bn_out ----------
__global__ void k_attn(const float* __restrict__ qa, const float* __restrict__ ka,
                       const float* __restrict__ va, const float* __restrict__ relAp,
                       const float* __restrict__ relATp, const float* __restrict__ veI,
                       const float* __restrict__ sg, const float* __restrict__ sb,
                       const float* __restrict__ og, const float* __restrict__ ob,
                       float* __restrict__ y) {
  int bg = blockIdx.x;
  int b = bg >> 3, g = bg & 7;
  int n = b >> 7, w = b & 127;
  __shared__ float Ss[65 * 68];
  __shared__ __half Pws[128 * 66];
  __shared__ float u0[1088];            // qs(520)|ksp(544) during sim; vas(16*68) after
  __shared__ float Pinvs[128];
  float* qs = u0;
  float* ksp = u0 + 520;
  float* vas = u0;
  int t = threadIdx.x;

  for (int l = t; l < 520; l += 256) qs[l] = qa[(size_t)bg * 520 + l];
  for (int l = t; l < 520; l += 256) {
    int c = l / 65, j = l - c * 65;
    ksp[c * 68 + j] = ka[(size_t)bg * 520 + l];
  }
  __syncthreads();

  // phase 2: sim 65x65 (BN-combined qk+qr+kr), j-quad vectorized
  {
    float sqk = sg[g] * RSBN, sqr = sg[8 + g] * RSBN, skr = sg[16 + g] * RSBN;
    float badd = sb[g] + sb[8 + g] + sb[16 + g];
    for (int u = t; u < 65 * 17; u += 256) {
      int i = u / 17, jq = u - i * 17;
      float qv[8];
      #pragma unroll
      for (int c = 0; c < 8; ++c) qv[c] = qs[c * 65 + i];
      if (jq < 16) {
        int j0 = jq * 4;
        int lofs = i * 68 + j0;
        float qk0 = 0, qk1 = 0, qk2 = 0, qk3 = 0;
        float qr0 = 0, qr1 = 0, qr2 = 0, qr3 = 0;
        float kr0 = 0, kr1 = 0, kr2 = 0, kr3 = 0;
        #pragma unroll
        for (int c = 0; c < 8; ++c) {
          float4 kv = *(const float4*)&ksp[c * 68 + j0];
          float4 ra = *(const float4*)&relAp[c * 4420 + lofs];
          float4 rt = *(const float4*)&relATp[c * 4420 + lofs];
          float q = qv[c];
          qk0 += q * kv.x; qk1 += q * kv.y; qk2 += q * kv.z; qk3 += q * kv.w;
          qr0 += q * ra.x; qr1 += q * ra.y; qr2 += q * ra.z; qr3 += q * ra.w;
          kr0 += kv.x * rt.x; kr1 += kv.y * rt.y; kr2 += kv.z * rt.z; kr3 += kv.w * rt.w;
        }
        float4 res;
        res.x = sqk * qk0 + sqr * qr0 + skr * kr0 + badd;
        res.y = sqk * qk1 + sqr * qr1 + skr * kr1 + badd;
        res.z = sqk * qk2 + sqr * qr2 + skr * kr2 + badd;
        res.w = sqk * qk3 + sqr * qr3 + skr * kr3 + badd;
        *(float4*)&Ss[lofs] = res;
      } else {
        float qk = 0, qr = 0, kr = 0;
        int lofs = i * 68 + 64;
        #pragma unroll
        for (int c = 0; c < 8; ++c) {
          float kv = ksp[c * 68 + 64];
          qk += qv[c] * kv;
          qr += qv[c] * relAp[c * 4420 + lofs];
          kr += kv * relATp[c * 4420 + lofs];
        }
        Ss[lofs] = sqk * qk + sqr * qr + skr * kr + badd;
      }
    }
  }
  __syncthreads();

  // phase 3: vas load (overlays u0) + register-T softmax fold
  for (int l = t; l < 16 * AA; l += 256) {
    int c = l / 65, a = l - c * 65;
    vas[c * 68 + a] = va[(size_t)bg * (16 * AA) + l];
  }
  {
    const int i = t >> 1, h = t & 1;
    int ia, ib; float fi;
    rz_taps(i, 65.0f / 128.0f, 65, ia, ib, fi);
    const float* r0 = Ss + ia * 68 + h * 32;
    const float* r1 = Ss + ib * 68 + h * 32;
    const float wi0 = 1.0f - fi;
    // T[k] = i-lerped 65-grid row (this half's 33 columns), in registers
    float T[33];
    #pragma unroll
    for (int k = 0; k < 33; ++k) T[k] = wi0 * r0[k] + fi * r1[k];
    float mx = T[0];
    #pragma unroll
    for (int k = 1; k < 33; ++k) mx = fmaxf(mx, T[k]);
    mx = fmaxf(mx, __shfl_xor(mx, 1));   // max over all T >= max over S128 row (convex combos)
    float p[33];
    #pragma unroll
    for (int k = 0; k < 33; ++k) p[k] = 0.f;
    float sum = 0.f;
    if (h == 0) {
      #pragma unroll
      for (int j = 0; j < 64; ++j) {
        JTAP(j, ja, jb, fj);
        float v = (1.0f - fj) * T[ja] + fj * T[jb];
        float e = __expf(v - mx);
        sum += e;
        p[ja] += e * (1.0f - fj);
        p[jb] += e * fj;
      }
    } else {
      #pragma unroll
      for (int j = 64; j < 128; ++j) {
        JTAP(j, ja, jb, fj);
        float v = (1.0f - fj) * T[ja - 32] + fj * T[jb - 32];
        float e = __expf(v - mx);
        sum += e;
        p[ja - 32] += e * (1.0f - fj);
        p[jb - 32] += e * fj;
      }
    }
    sum += __shfl_xor(sum, 1);
    float other = __shfl_xor(h ? p[0] : p[32], 1);
    __half* prow = &Pws[i * 66];
    if (h == 0) {
      p[32] += other;
      #pragma unroll
      for (int k = 0; k < 33; ++k) prow[k] = __float2half(p[k]);
      Pinvs[i] = 1.0f / sum;
    } else {
      p[0] += other;
      #pragma unroll
      for (int k = 0; k < 33; ++k) prow[32 + k] = __float2half(p[k]);
    }
  }
  __syncthreads();

  // phase 4: sv/sve contraction; each thread owns one i and 8 c's (prow amortized)
  {
    const int i = t & 127;
    const int cg = t >> 7;
    const float inv = Pinvs[i];
    float2 acc[8];
    #pragma unroll
    for (int l = 0; l < 8; ++l) { acc[l].x = 0.f; acc[l].y = 0.f; }
    const __half* prow = &Pws[i * 66];
    #pragma unroll
    for (int chk = 0; chk < 8; ++chk) {
      const int a0 = chk * 8;
      float pv[8];
      #pragma unroll
      for (int q2 = 0; q2 < 4; ++q2) {
        float2 f2 = __half22float2(*(const __half2*)(prow + a0 + 2 * q2));
        pv[2 * q2] = f2.x; pv[2 * q2 + 1] = f2.y;
      }
      #pragma unroll
      for (int l = 0; l < 8; ++l) {
        const int c = cg + 2 * l;
        const float* vr = &vas[c * 68 + a0];
        const float* vp = veI + ((size_t)(c * 65 + a0)) * 128 + i;
        #pragma unroll
        for (int k = 0; k < 8; ++k) {
          acc[l].x += pv[k] * vr[k];
          acc[l].y += pv[k] * vp[(size_t)k * 128];
        }
      }
    }
    {
      float p64 = __half2float(prow[64]);
      #pragma unroll
      for (int l = 0; l < 8; ++l) {
        const int c = cg + 2 * l;
        acc[l].x += p64 * vas[c * 68 + 64];
        acc[l].y += p64 * veI[((size_t)(c * 65 + 64)) * 128 + i];
      }
    }
    #pragma unroll
    for (int l = 0; l < 8; ++l) {
      const int c = cg + 2 * l;
      int c2 = g * 16 + c;
      int o0 = 2 * c2;
      float sv = acc[l].x * inv, sve = acc[l].y * inv;
      float val = og[o0] * RSBN * sv + ob[o0] + og[o0 + 1] * RSBN * sve + ob[o0 + 1];
      y[(((size_t)n * 128 + c2) * 128 + i) * 128 + w] = val;
    }
  }
}

// ---------- block reduce helper ----------
__device__ __forceinline__ float2 blockRed2(float a, float b, float* sm) {
  #pragma unroll
  for (int o = 32; o; o >>= 1) { a += __shfl_down(a, o); b += __shfl_down(b, o); }
  int t = threadIdx.x, wv = t >> 6;
  __syncthreads();
  if ((t & 63) == 0) { sm[wv * 2] = a; sm[wv * 2 + 1] = b; }
  __syncthreads();
  return make_float2(sm[0] + sm[2] + sm[4] + sm[6], sm[1] + sm[3] + sm[5] + sm[7]);
}

// ---------- G1: per-channel sums + strip sums; materialize 40 shifted channels ----------
__global__ void k_stats(const float* __restrict__ y, float* __restrict__ xsh,
                        float* __restrict__ stat) {
  int nc = blockIdx.x;
  int n = nc >> 7, c = nc & 127;
  if (c >= 10 && c < 40) return;
  __shared__ float sm[8];
  const float* src = y + (size_t)nc * 16384;
  int t = threadIdx.x;
  float s = 0.f, q = 0.f;
  for (int l = 0; l < 64; ++l) {
    float v = src[t + l * 256];
    s += v; q += v * v;
  }
  float2 SQ = blockRed2(s, q, sm);
  if (c < 10) {
    float v;
    v = src[(t >> 1) * 128 + (t & 1)];            float2 cL = blockRed2(v, v * v, sm);
    v = src[(t >> 1) * 128 + 126 + (t & 1)];      float2 cH = blockRed2(v, v * v, sm);
    v = src[(t >> 7) * 128 + (t & 127)];          float2 rL = blockRed2(v, v * v, sm);
    v = src[(126 + (t >> 7)) * 128 + (t & 127)];  float2 rH = blockRed2(v, v * v, sm);
    if (t == 0) {
      float* st = stat + nc * 10;
      st[0] = SQ.x; st[1] = SQ.y; st[2] = cL.x; st[3] = cL.y; st[4] = cH.x;
      st[5] = cH.y; st[6] = rL.x; st[7] = rL.y; st[8] = rH.x; st[9] = rH.y;
    }
    float* dR = xsh + (size_t)(n * 40 + c) * 16384;
    float* dL = xsh + (size_t)(n * 40 + 10 + c) * 16384;
    float* dD = xsh + (size_t)(n * 40 + 20 + c) * 16384;
    float* dU = xsh + (size_t)(n * 40 + 30 + c) * 16384;
    for (int l = 0; l < 64; ++l) {
      int idx = t + l * 256;
      int h = idx >> 7, w = idx & 127;
      dR[idx] = (w >= 2) ? src[idx - 2] : 0.f;
      dL[idx] = (w <= 125) ? src[idx + 2] : 0.f;
      dD[idx] = (h >= 2) ? src[idx - 256] : 0.f;
      dU[idx] = (h <= 125) ? src[idx + 256] : 0.f;
    }
  } else if (t == 0) {
    stat[nc * 10] = SQ.x; stat[nc * 10 + 1] = SQ.y;
  }
}

// ---------- G2: finalize instance-norm scale/shift ----------
__global__ void k_fin(const float* __restrict__ stat, const float* __restrict__ inw,
                      const float* __restrict__ inb, float* __restrict__ ss) {
  int t = threadIdx.x;  // 256 = n*128+cx
  int n = t >> 7, cx = t & 127;
  float S, Q;
  if (cx < 40) {
    int c = cx % 10;
    const float* st = stat + (size_t)(n * 128 + c) * 10;
    int grp = cx / 10;
    if (grp == 0)      { S = st[0] - st[4]; Q = st[1] - st[5]; }  // right: excl colHi
    else if (grp == 1) { S = st[0] - st[2]; Q = st[1] - st[3]; }  // left: excl colLo
    else if (grp == 2) { S = st[0] - st[8]; Q = st[1] - st[9]; }  // down: excl rowHi
    else               { S = st[0] - st[6]; Q = st[1] - st[7]; }  // up: excl rowLo
  } else {
    const float* st = stat + (size_t)(n * 128 + cx) * 10;
    S = st[0]; Q = st[1];
  }
  float mean = S * (1.0f / 16384.0f);
  float var = Q * (1.0f / 16384.0f) - mean * mean;
  float scale = inw[cx] * rsqrtf(var + 1e-5f);
  ss[2 * t] = scale;
  ss[2 * t + 1] = inb[cx] - mean * scale;
}

// ---------- MFMA GEMM 2: h1 = gelu(W1 . xn); shift-on-load from y/xsh ----------
__global__ __launch_bounds__(256) void k_mlp1_mfma(
    const float* __restrict__ y, const float* __restrict__ xsh,
    const float* __restrict__ ss, const short* __restrict__ w1b,
    short* __restrict__ h1) {
  const int ob = blockIdx.x * 128;
  const int pb = blockIdx.y * 128;
  const int n = blockIdx.z;
  __shared__ short Asm[128 * 40];
  __shared__ short Bsm[128 * 40];
  const int t = threadIdx.x;
  const int lane = t & 63, wv = t >> 6;
  const int wm = wv >> 1, wn = wv & 1;
  const int lr = lane & 15, lk = (lane >> 4) * 8;
  f32x4 acc[4][4];
  #pragma unroll
  for (int a = 0; a < 4; ++a)
    #pragma unroll
    for (int b = 0; b < 4; ++b)
      #pragma unroll
      for (int q = 0; q < 4; ++q) acc[a][b][q] = 0.f;
  const float* Yn = y + (size_t)n * 128 * 16384;
  const float* Xs = xsh + (size_t)n * 40 * 16384;
  for (int k0 = 0; k0 < 128; k0 += 32) {
    #pragma unroll
    for (int i2 = 0; i2 < 2; ++i2) {
      int u = t + 256 * i2;
      int row = u >> 2, kq = (u & 3) * 8;
      *(bf16x8*)&Asm[row * 40 + kq] = *(const bf16x8*)&w1b[(ob + row) * 128 + k0 + kq];
    }
    #pragma unroll
    for (int i4 = 0; i4 < 4; ++i4) {
      int u = t + 256 * i4;
      int k = u >> 5, p4 = (u & 31) * 4;
      int ch = k0 + k;
      float sc = ss[2 * (n * 128 + ch)];
      float sh = ss[2 * (n * 128 + ch) + 1];
      const float* srcp = (ch < 40) ? Xs + (size_t)ch * 16384 : Yn + (size_t)ch * 16384;
      float4 xv = *(const float4*)&srcp[pb + p4];
      Bsm[(p4 + 0) * 40 + k] = f2b(xv.x * sc + sh);
      Bsm[(p4 + 1) * 40 + k] = f2b(xv.y * sc + sh);
      Bsm[(p4 + 2) * 40 + k] = f2b(xv.z * sc + sh);
      Bsm[(p4 + 3) * 40 + k] = f2b(xv.w * sc + sh);
    }
    __syncthreads();
    bf16x8 af[4], bfr[4];
    #pragma unroll
    for (int mf = 0; mf < 4; ++mf) af[mf] = *(bf16x8*)&Asm[(wm * 64 + mf * 16 + lr) * 40 + lk];
    #pragma unroll
    for (int nf = 0; nf < 4; ++nf) bfr[nf] = *(bf16x8*)&Bsm[(wn * 64 + nf * 16 + lr) * 40 + lk];
    #pragma unroll
    for (int mf = 0; mf < 4; ++mf)
      #pragma unroll
      for (int nf = 0; nf < 4; ++nf)
        acc[mf][nf] = MFMA16(af[mf], bfr[nf], acc[mf][nf]);
    __syncthreads();
  }
  #pragma unroll
  for (int mf = 0; mf < 4; ++mf)
    #pragma unroll
    for (int r = 0; r < 4; ++r) {
      int o = ob + wm * 64 + mf * 16 + (lane >> 4) * 4 + r;
      #pragma unroll
      for (int nf = 0; nf < 4; ++nf) {
        int p = pb + wn * 64 + nf * 16 + lr;
        h1[((size_t)(n * 512 + o)) * 16384 + p] = f2b(gelu_exact(acc[mf][nf][r]));
      }
    }
}

// ---------- MFMA GEMM 3: out = W2 . h1 + identity(y) ----------
__global__ __launch_bounds__(256) void k_mlp2_mfma(
    const short* __restrict__ h1, const short* __restrict__ w2b,
    const float* __restrict__ y, float* __restrict__ out) {
  const int pb = blockIdx.x * 128;
  const int ob = blockIdx.y * 128;
  const int n = blockIdx.z;
  __shared__ short Asm[128 * 40];
  __shared__ short Bsm[128 * 40];
  const int t = threadIdx.x;
  const int lane = t & 63, wv = t >> 6;
  const int wm = wv >> 1, wn = wv & 1;
  const int lr = lane & 15, lk = (lane >> 4) * 8;
  f32x4 acc[4][4];
  #pragma unroll
  for (int a = 0; a < 4; ++a)
    #pragma unroll
    for (int b = 0; b < 4; ++b)
      #pragma unroll
      for (int q = 0; q < 4; ++q) acc[a][b][q] = 0.f;
  const short* H = h1 + (size_t)n * 512 * 16384;
  for (int k0 = 0; k0 < 512; k0 += 32) {
    #pragma unroll
    for (int i2 = 0; i2 < 2; ++i2) {
      int u = t + 256 * i2;
      int row = u >> 2, kq = (u & 3) * 8;
      *(bf16x8*)&Asm[row * 40 + kq] = *(const bf16x8*)&w2b[(ob + row) * 512 + k0 + kq];
    }
    #pragma unroll
    for (int i2 = 0; i2 < 2; ++i2) {
      int u = t + 256 * i2;
      int k = u >> 4, p8 = (u & 15) * 8;
      bf16x8 hv = *(const bf16x8*)&H[(size_t)(k0 + k) * 16384 + pb + p8];
      #pragma unroll
      for (int j = 0; j < 8; ++j) Bsm[(p8 + j) * 40 + k] = hv[j];
    }
    __syncthreads();
    bf16x8 af[4], bfr[4];
    #pragma unroll
    for (int mf = 0; mf < 4; ++mf) af[mf] = *(bf16x8*)&Asm[(wm * 64 + mf * 16 + lr) * 40 + lk];
    #pragma unroll
    for (int nf = 0; nf < 4; ++nf) bfr[nf] = *(bf16x8*)&Bsm[(wn * 64 + nf * 16 + lr) * 40 + lk];
    #pragma unroll
    for (int mf = 0; mf < 4; ++mf)
      #pragma unroll
      for (int nf = 0; nf < 4; ++nf)
        acc[mf][nf] = MFMA16(af[mf], bfr[nf], acc[mf][nf]);
    __syncthreads();
  }
  #pragma unroll
  for (int mf = 0; mf < 4; ++mf)
    #pragma unroll
    for (int r = 0; r < 4; ++r) {
      int o = ob + wm * 64 + mf * 16 + (lane >> 4) * 4 + r;
      #pragma unroll
      for (int nf = 0; nf < 4; ++nf) {
        int p = pb + wn * 64 + nf * 16 + lr;
        size_t base = ((size_t)(n * 128 + o)) * 16384 + p;
        out[base] = acc[mf][nf][r] + y[base];
      }
    }
}

extern "C" void kernel_launch(void* const* d_in, const int* in_sizes, int n_in,
                              void* d_out, int out_size, void* d_ws, size_t ws_size,
                              hipStream_t stream) {
  const float* x        = (const float*)d_in[0];
  const float* w_qkv    = (const float*)d_in[1];
  const float* bn_qkv_g = (const float*)d_in[2];
  const float* bn_qkv_b = (const float*)d_in[3];
  const float* bn_sim_g = (const float*)d_in[4];
  const float* bn_sim_b = (const float*)d_in[5];
  const float* bn_out_g = (const float*)d_in[6];
  const float* bn_out_b = (const float*)d_in[7];
  const float* in_w     = (const float*)d_in[8];
  const float* in_b     = (const float*)d_in[9];
  const float* mlp_w1   = (const float*)d_in[10];
  const float* mlp_w2   = (const float*)d_in[11];
  const float* base_rel = (const float*)d_in[12];
  float* Wp = (float*)d_ws;

  float* relA   = Wp + 0;          // 135,200 (pad 135,424)
  float* relAp  = Wp + 135424;     // 35,360 (pad 35,456)
  float* relATp = Wp + 170880;     // 35,456
  float* veI    = Wp + 206336;     // 133,120 (pad 133,376)
  float* qa     = Wp + 339712;     // 1,064,960
  float* ka     = Wp + 1404672;    // 1,064,960
  float* va     = Wp + 2469632;    // 2,129,920
  float* yb     = Wp + 4599552;    // 4,194,304
  float* ssb    = Wp + 8793856;    // 1,024
  float* statb  = Wp + 8794880;    // 2,560
  float* xsh    = Wp + 8797440;    // 1,310,720
  short* wqb    = (short*)(Wp + 10108160);   // 32,768 shorts
  short* w1b    = (short*)(Wp + 10124544);   // 65,536 shorts
  short* w2b    = (short*)(Wp + 10157312);   // 65,536 shorts
  float* qkv    = Wp + 10190080;   // 8,388,608 (dead after k_down)
  short* h1b    = (short*)(Wp + 10190080);   // overlays qkv (same size)
  // peak: 18,578,688 floats = 74.3 MB

  k_wbf<<<dim3(256), dim3(256), 0, stream>>>(w_qkv, mlp_w1, mlp_w2, wqb, w1b, w2b);
  k_relA<<<dim3(529), dim3(256), 0, stream>>>(base_rel, relA, relAp, relATp);
  k_vei<<<dim3(520), dim3(256), 0, stream>>>(relA, veI);
  k_qkv_mfma<<<dim3(2, 128, 2), dim3(256), 0, stream>>>(x, wqb, bn_qkv_g, bn_qkv_b, qkv);
  k_down<<<dim3(16640), dim3(256), 0, stream>>>(qkv, qa, ka, va);
  k_attn<<<dim3(2048), dim3(256), 0, stream>>>(qa, ka, va, relAp, relATp, veI,
                                               bn_sim_g, bn_sim_b, bn_out_g, bn_out_b, yb);
  k_stats<<<dim3(256), dim3(256), 0, stream>>>(yb, xsh, statb);
  k_fin<<<dim3(1), dim3(256), 0, stream>>>(statb, in_w, in_b, ssb);
  k_mlp1_mfma<<<dim3(4, 128, 2), dim3(256), 0, stream>>>(yb, xsh, ssb, w1b, h1b);
  k_mlp2_mfma<<<dim3(128, 1, 2), dim3(256), 0, stream>>>(h1b, w2b, yb, (float*)d_out);
}

// Round 6
// 223.596 us; speedup vs baseline: 1.1789x; 1.1789x over previous
//
#include <hip/hip_runtime.h>
#include <hip/hip_bf16.h>
#include <hip/hip_fp16.h>

#define GG 8
#define AA 65
#define BB 256

typedef __attribute__((ext_vector_type(8))) short bf16x8;
typedef __attribute__((ext_vector_type(4))) short s16x4;
typedef __attribute__((ext_vector_type(4))) float f32x4;
typedef _Float16 hf2 __attribute__((ext_vector_type(2)));
#define MFMA16(a, b, c) __builtin_amdgcn_mfma_f32_16x16x32_bf16(a, b, c, 0, 0, 0)

__device__ __forceinline__ void rz_taps(int o, float scale, int in_size,
                                        int& ia, int& ib, float& f) {
  float pos = (o + 0.5f) * scale - 0.5f;
  float fl = floorf(pos);
  int i0 = (int)fl;
  f = pos - fl;
  ia = i0 < 0 ? 0 : i0;
  int i1 = i0 + 1;
  ib = i1 > (in_size - 1) ? (in_size - 1) : i1;
}

// Compile-time 128->65 tap: pos = (j+0.5)*65/128-0.5 = (130j-63)/256 exactly.
#define JTAP(jc, ja, jb, fj) \
  const int num_ = 130 * (jc) - 63;               \
  const int fl_ = num_ >> 8;                      \
  const int ja = fl_ < 0 ? 0 : fl_;               \
  const int jb = (fl_ + 1 > 64) ? 64 : (fl_ + 1); \
  const float fj = (float)(num_ - (fl_ << 8)) * 0.00390625f;

__device__ __forceinline__ float gelu_exact(float v) {
  return 0.5f * v * (1.0f + erff(v * 0.70710678118654752f));
}

__device__ __forceinline__ short f2b(float f) {
  __hip_bfloat16 h = __float2bfloat16(f);
  return *reinterpret_cast<short*>(&h);
}
__device__ __forceinline__ float b2f(short s) {
  unsigned int u = ((unsigned int)(unsigned short)s) << 16;
  return __uint_as_float(u);
}

#define RSBN 0.99999500003749977f  // 1/sqrt(1+1e-5)

// ---------- W: weights -> bf16 ----------
__global__ void k_wbf(const float* __restrict__ wq, const float* __restrict__ w1,
                      const float* __restrict__ w2, short* __restrict__ wqb,
                      short* __restrict__ w1b, short* __restrict__ w2b) {
  int i = blockIdx.x * 256 + threadIdx.x;
  if (i < 32768) wqb[i] = f2b(wq[i]);
  if (i < 65536) { w1b[i] = f2b(w1[i]); w2b[i] = f2b(w2[i]); }
}

// ---------- X: x -> bf16 ----------
__global__ void k_xb(const float* __restrict__ x, short* __restrict__ xb) {
  int q = blockIdx.x * 256 + threadIdx.x;  // x8 elems, 2048 blocks
  const float4 a = *(const float4*)&x[(size_t)q * 8];
  const float4 b = *(const float4*)&x[(size_t)q * 8 + 4];
  bf16x8 o;
  o[0] = f2b(a.x); o[1] = f2b(a.y); o[2] = f2b(a.z); o[3] = f2b(a.w);
  o[4] = f2b(b.x); o[5] = f2b(b.y); o[6] = f2b(b.z); o[7] = f2b(b.w);
  *(bf16x8*)&xb[(size_t)q * 8] = o;
}

// ---------- A: base_relative -> relA (32,65,65) + padded q/k copies ----------
__global__ void k_relA(const float* __restrict__ base, float* __restrict__ relA,
                       float* __restrict__ relAp, float* __restrict__ relATp) {
  int idx = blockIdx.x * 256 + threadIdx.x;
  if (idx >= 32 * AA * AA) return;
  int j = idx % AA;
  int r = idx / AA;
  int i = r % AA;
  int c = r / AA;
  int ia, ib, ja, jb; float fi, fj;
  rz_taps(i, 255.0f / 65.0f, 255, ia, ib, fi);
  rz_taps(j, 255.0f / 65.0f, 255, ja, jb, fj);
  const float* S = base + (size_t)c * 255 * 255;
  float v = (1.0f - fi) * ((1.0f - fj) * S[ia * 255 + ja] + fj * S[ia * 255 + jb])
          + fi * ((1.0f - fj) * S[ib * 255 + ja] + fj * S[ib * 255 + jb]);
  relA[idx] = v;
  if (c < 8) relAp[c * 4420 + i * 68 + j] = v;
  else if (c < 16) relATp[(c - 8) * 4420 + j * 68 + i] = v;
}

// ---------- B: veA half2 layout: dword (c*33+ap)*128+i holds (a=2ap, a=2ap+1) ----------
__global__ void k_vei(const float* __restrict__ relA, __half* __restrict__ veA) {
  int idx = blockIdx.x * 256 + threadIdx.x;  // 16*66*128 = 135,168
  if (idx >= 16 * 66 * 128) return;
  int i = idx & 127;
  int r = idx >> 7;
  int a = r % 66, c = r / 66;
  float v = 0.f;
  if (a < 65) {
    int ia, ib; float fi;
    rz_taps(i, 65.0f / 128.0f, 65, ia, ib, fi);
    const float* S = relA + (size_t)(16 + c) * (AA * AA);
    v = (1.0f - fi) * S[ia * AA + a] + fi * S[ib * AA + a];
  }
  veA[((size_t)(c * 33 + (a >> 1)) * 128 + i) * 2 + (a & 1)] = __float2half(v);
}

// ---------- MFMA GEMM 1: qkvb = bf16(BN(Wqkv . x)) ----------
__global__ __launch_bounds__(256) void k_qkv_mfma(
    const short* __restrict__ xb, const short* __restrict__ wqb,
    const float* __restrict__ bg, const float* __restrict__ bb,
    short* __restrict__ out) {
  const int ob = blockIdx.x * 128;
  const int pb = blockIdx.y * 128;
  const int n = blockIdx.z;
  __shared__ short Asm[128 * 40];
  __shared__ short Bsm[128 * 40];
  const int t = threadIdx.x;
  const int lane = t & 63, wv = t >> 6;
  const int wm = wv >> 1, wn = wv & 1;
  const int lr = lane & 15, lk = (lane >> 4) * 8;
  f32x4 acc[4][4];
  #pragma unroll
  for (int a = 0; a < 4; ++a)
    #pragma unroll
    for (int b = 0; b < 4; ++b)
      #pragma unroll
      for (int q = 0; q < 4; ++q) acc[a][b][q] = 0.f;
  const short* X = xb + (size_t)n * 128 * 16384;
  for (int k0 = 0; k0 < 128; k0 += 32) {
    #pragma unroll
    for (int i2 = 0; i2 < 2; ++i2) {
      int u = t + 256 * i2;
      int row = u >> 2, kq = (u & 3) * 8;
      *(bf16x8*)&Asm[row * 40 + kq] = *(const bf16x8*)&wqb[(ob + row) * 128 + k0 + kq];
    }
    #pragma unroll
    for (int i2 = 0; i2 < 2; ++i2) {
      int u = t + 256 * i2;
      int k = u >> 4, p8 = (u & 15) * 8;
      bf16x8 hv = *(const bf16x8*)&X[(size_t)(k0 + k) * 16384 + pb + p8];
      #pragma unroll
      for (int j = 0; j < 8; ++j) Bsm[(p8 + j) * 40 + k] = hv[j];
    }
    __syncthreads();
    bf16x8 af[4], bfr[4];
    #pragma unroll
    for (int mf = 0; mf < 4; ++mf) af[mf] = *(bf16x8*)&Asm[(wm * 64 + mf * 16 + lr) * 40 + lk];
    #pragma unroll
    for (int nf = 0; nf < 4; ++nf) bfr[nf] = *(bf16x8*)&Bsm[(wn * 64 + nf * 16 + lr) * 40 + lk];
    #pragma unroll
    for (int mf = 0; mf < 4; ++mf)
      #pragma unroll
      for (int nf = 0; nf < 4; ++nf)
        acc[mf][nf] = MFMA16(af[mf], bfr[nf], acc[mf][nf]);
    __syncthreads();
  }
  #pragma unroll
  for (int mf = 0; mf < 4; ++mf) {
    #pragma unroll
    for (int r = 0; r < 4; ++r) {
      int o = ob + wm * 64 + mf * 16 + (lane >> 4) * 4 + r;
      float sc = bg[o] * RSBN, sh = bb[o];
      #pragma unroll
      for (int nf = 0; nf < 4; ++nf) {
        int p = pb + wn * 64 + nf * 16 + lr;
        out[((size_t)(n * 256 + o)) * 16384 + p] = f2b(acc[mf][nf][r] * sc + sh);
      }
    }
  }
}

// ---------- D: downsample qkvb along i (128->65), split ----------
__global__ void k_down(const short* __restrict__ qkvb, float* __restrict__ qa,
                       float* __restrict__ ka, float* __restrict__ va) {
  int idx = blockIdx.x * 256 + threadIdx.x;
  if (idx >= BB * GG * 32 * AA) return;
  int w = idx & 127;
  int r = idx >> 7;
  int a = r % AA; r /= AA;
  int cc = r & 31; r >>= 5;
  int g = r & 7;
  int n = r >> 3;
  int o = g * 32 + cc;
  int ia, ib; float f;
  rz_taps(a, 128.0f / 65.0f, 128, ia, ib, f);
  const short* src = qkvb + ((size_t)(n * 256 + o)) * 16384 + w;
  float v = (1.0f - f) * b2f(src[ia * 128]) + f * b2f(src[ib * 128]);
  int bg = (n * 128 + w) * 8 + g;
  if (cc < 8)       qa[((size_t)bg * 8 + cc) * AA + a] = v;
  else if (cc < 16) ka[((size_t)bg * 8 + (cc - 8)) * AA + a] = v;
  else              va[((size_t)bg * 16 + (cc - 16)) * AA + a] = v;
}

// ---------- F: fused sim + softmax(register-T fold) + dot2 sv/sve + bn_out ----------
__global__ void k_attn(const float* __restrict__ qa, const float* __restrict__ ka,
                       const float* __restrict__ va, const float* __restrict__ relAp,
                       const float* __restrict__ relATp, const __half* __restrict__ veA,
                       const float* __restrict__ sg, const float* __restrict__ sb,
                       const float* __restrict__ og, const float* __restrict__ ob,
                       float* __restrict__ y) {
  int bg = blockIdx.x;
  int b = bg >> 3, g = bg & 7;
  int n = b >> 7, w = b & 127;
  __shared__ float Ss[65 * 68];          // 17,680 B
  __shared__ __half PwsH[128 * 66];      // 16,896 B (66 = 33 a-pairs)
  __shared__ float u0[1088];             // qs(520)|ksp(544); vasH (16*66 halves) after
  __shared__ float Pinvs[128];
  float* qs = u0;
  float* ksp = u0 + 520;
  __half* vasH = (__half*)u0;
  int t = threadIdx.x;

  for (int l = t; l < 520; l += 256) qs[l] = qa[(size_t)bg * 520 + l];
  for (int l = t; l < 520; l += 256) {
    int c = l / 65, j = l - c * 65;
    ksp[c * 68 + j] = ka[(size_t)bg * 520 + l];
  }
  __syncthreads();

  // phase 2: sim 65x65 (BN-combined qk+qr+kr), j-quad vectorized
  {
    float sqk = sg[g] * RSBN, sqr = sg[8 + g] * RSBN, skr = sg[16 + g] * RSBN;
    float badd = sb[g] + sb[8 + g] + sb[16 + g];
    for (int u = t; u < 65 * 17; u += 256) {
      int i = u / 17, jq = u - i * 17;
      float qv[8];
      #pragma unroll
      for (int c = 0; c < 8; ++c) qv[c] = qs[c * 65 + i];
      if (jq < 16) {
        int j0 = jq * 4;
        int lofs = i * 68 + j0;
        float qk0 = 0, qk1 = 0, qk2 = 0, qk3 = 0;
        float qr0 = 0, qr1 = 0, qr2 = 0, qr3 = 0;
        float kr0 = 0, kr1 = 0, kr2 = 0, kr3 = 0;
        #pragma unroll
        for (int c = 0; c < 8; ++c) {
          float4 kv = *(const float4*)&ksp[c * 68 + j0];
          float4 ra = *(const float4*)&relAp[c * 4420 + lofs];
          float4 rt = *(const float4*)&relATp[c * 4420 + lofs];
          float q = qv[c];
          qk0 += q * kv.x; qk1 += q * kv.y; qk2 += q * kv.z; qk3 += q * kv.w;
          qr0 += q * ra.x; qr1 += q * ra.y; qr2 += q * ra.z; qr3 += q * ra.w;
          kr0 += kv.x * rt.x; kr1 += kv.y * rt.y; kr2 += kv.z * rt.z; kr3 += kv.w * rt.w;
        }
        float4 res;
        res.x = sqk * qk0 + sqr * qr0 + skr * kr0 + badd;
        res.y = sqk * qk1 + sqr * qr1 + skr * kr1 + badd;
        res.z = sqk * qk2 + sqr * qr2 + skr * kr2 + badd;
        res.w = sqk * qk3 + sqr * qr3 + skr * kr3 + badd;
        *(float4*)&Ss[lofs] = res;
      } else {
        float qk = 0, qr = 0, kr = 0;
        int lofs = i * 68 + 64;
        #pragma unroll
        for (int c = 0; c < 8; ++c) {
          float kv = ksp[c * 68 + 64];
          qk += qv[c] * kv;
          qr += qv[c] * relAp[c * 4420 + lofs];
          kr += kv * relATp[c * 4420 + lofs];
        }
        Ss[lofs] = sqk * qk + sqr * qr + skr * kr + badd;
      }
    }
  }
  __syncthreads();

  // phase 3: vasH load (fp16, a padded to 66) + register-T softmax fold
  for (int l = t; l < 16 * 66; l += 256) {
    int c = l / 66, a = l - c * 66;
    float v = (a < 65) ? va[(size_t)bg * (16 * AA) + c * 65 + a] : 0.f;
    vasH[l] = __float2half(v);
  }
  {
    const int i = t >> 1, h = t & 1;
    int ia, ib; float fi;
    rz_taps(i, 65.0f / 128.0f, 65, ia, ib, fi);
    const float* r0 = Ss + ia * 68 + h * 32;
    const float* r1 = Ss + ib * 68 + h * 32;
    const float wi0 = 1.0f - fi;
    float T[33];
    #pragma unroll
    for (int k = 0; k < 33; ++k) T[k] = wi0 * r0[k] + fi * r1[k];
    float mx = T[0];
    #pragma unroll
    for (int k = 1; k < 33; ++k) mx = fmaxf(mx, T[k]);
    mx = fmaxf(mx, __shfl_xor(mx, 1));
    float p[33];
    #pragma unroll
    for (int k = 0; k < 33; ++k) p[k] = 0.f;
    float sum = 0.f;
    if (h == 0) {
      #pragma unroll
      for (int j = 0; j < 64; ++j) {
        JTAP(j, ja, jb, fj);
        float v = (1.0f - fj) * T[ja] + fj * T[jb];
        float e = __expf(v - mx);
        sum += e;
        p[ja] += e * (1.0f - fj);
        p[jb] += e * fj;
      }
    } else {
      #pragma unroll
      for (int j = 64; j < 128; ++j) {
        JTAP(j, ja, jb, fj);
        float v = (1.0f - fj) * T[ja - 32] + fj * T[jb - 32];
        float e = __expf(v - mx);
        sum += e;
        p[ja - 32] += e * (1.0f - fj);
        p[jb - 32] += e * fj;
      }
    }
    sum += __shfl_xor(sum, 1);
    float other = __shfl_xor(h ? p[0] : p[32], 1);
    __half* prow = &PwsH[i * 66];
    if (h == 0) {
      p[32] += other;
      #pragma unroll
      for (int k = 0; k < 33; ++k) prow[k] = __float2half(p[k]);
      Pinvs[i] = 1.0f / sum;
    } else {
      p[0] += other;
      #pragma unroll
      for (int k = 0; k < 33; ++k) prow[32 + k] = __float2half(p[k]);
      prow[65] = __float2half(0.f);
    }
  }
  __syncthreads();

  // phase 4: dot2 contraction over 33 a-pairs; thread = (i, c-half)
  {
    const int i = t & 127;
    const int cg = t >> 7;
    const float inv = Pinvs[i];
    hf2 pw[33];
    const hf2* prow2 = (const hf2*)&PwsH[i * 66];
    #pragma unroll
    for (int ap = 0; ap < 33; ++ap) pw[ap] = prow2[ap];
    #pragma unroll
    for (int l = 0; l < 8; ++l) {
      const int c = cg * 8 + l;
      const hf2* vr = (const hf2*)&vasH[c * 66];
      const hf2* vp = (const hf2*)veA + (size_t)(c * 33) * 128 + i;
      float sv = 0.f, se = 0.f;
      #pragma unroll
      for (int ap = 0; ap < 33; ++ap) {
        sv = __builtin_amdgcn_fdot2(vr[ap], pw[ap], sv, false);
        se = __builtin_amdgcn_fdot2(vp[(size_t)ap * 128], pw[ap], se, false);
      }
      int c2 = g * 16 + c;
      int o0 = 2 * c2;
      float val = og[o0] * RSBN * (sv * inv) + ob[o0]
                + og[o0 + 1] * RSBN * (se * inv) + ob[o0 + 1];
      y[(((size_t)n * 128 + c2) * 128 + i) * 128 + w] = val;
    }
  }
}

// ---------- G: unified shift + instance-norm + bf16 write (one block per out-channel) ----------
__global__ __launch_bounds__(256) void k_xn(const float* __restrict__ y,
                                            const float* __restrict__ inw,
                                            const float* __restrict__ inb,
                                            short* __restrict__ xnb) {
  int nc = blockIdx.x;
  int n = nc >> 7, cx = nc & 127;
  int sc_ch = cx, dh = 0, dw = 0;
  if (cx < 10)      { sc_ch = cx;      dw = -2; }
  else if (cx < 20) { sc_ch = cx - 10; dw = 2; }
  else if (cx < 30) { sc_ch = cx - 20; dh = -2; }
  else if (cx < 40) { sc_ch = cx - 30; dh = 2; }
  __shared__ short Sb[16384];   // bf16 stage of source plane, 32 KB
  __shared__ float sm[8];
  const float* src = y + ((size_t)n * 128 + sc_ch) * 16384;
  int t = threadIdx.x;
  #pragma unroll
  for (int l = 0; l < 16; ++l) {
    int q = t + l * 256;
    float4 v = *(const float4*)&src[q * 4];
    s16x4 o;
    o.x = f2b(v.x); o.y = f2b(v.y); o.z = f2b(v.z); o.w = f2b(v.w);
    *(s16x4*)&Sb[q * 4] = o;
  }
  __syncthreads();
  float s = 0.f, q2 = 0.f;
  for (int l = 0; l < 64; ++l) {
    int idx = t + l * 256;
    int h = idx >> 7, w = idx & 127;
    int hs = h + dh, ws = w + dw;
    float v = (hs >= 0 && hs < 128 && ws >= 0 && ws < 128) ? b2f(Sb[hs * 128 + ws]) : 0.f;
    s += v; q2 += v * v;
  }
  #pragma unroll
  for (int o = 32; o; o >>= 1) { s += __shfl_down(s, o); q2 += __shfl_down(q2, o); }
  if ((t & 63) == 0) { sm[(t >> 6) * 2] = s; sm[(t >> 6) * 2 + 1] = q2; }
  __syncthreads();
  float S_ = sm[0] + sm[2] + sm[4] + sm[6];
  float Q_ = sm[1] + sm[3] + sm[5] + sm[7];
  float mean = S_ * (1.0f / 16384.0f);
  float var = Q_ * (1.0f / 16384.0f) - mean * mean;
  float scale = inw[cx] * rsqrtf(var + 1e-5f);
  float shift = inb[cx] - mean * scale;
  short* dst = xnb + (size_t)nc * 16384;
  for (int l = 0; l < 64; ++l) {
    int idx = t + l * 256;
    int h = idx >> 7, w = idx & 127;
    int hs = h + dh, ws = w + dw;
    float v = (hs >= 0 && hs < 128 && ws >= 0 && ws < 128) ? b2f(Sb[hs * 128 + ws]) : 0.f;
    dst[idx] = f2b(v * scale + shift);
  }
}

// ---------- MFMA GEMM 2: h1 = gelu(W1 . xn), pure bf16 staging ----------
__global__ __launch_bounds__(256) void k_mlp1_mfma(
    const short* __restrict__ xnb, const short* __restrict__ w1b,
    short* __restrict__ h1) {
  const int ob = blockIdx.x * 128;
  const int pb = blockIdx.y * 128;
  const int n = blockIdx.z;
  __shared__ short Asm[128 * 40];
  __shared__ short Bsm[128 * 40];
  const int t = threadIdx.x;
  const int lane = t & 63, wv = t >> 6;
  const int wm = wv >> 1, wn = wv & 1;
  const int lr = lane & 15, lk = (lane >> 4) * 8;
  f32x4 acc[4][4];
  #pragma unroll
  for (int a = 0; a < 4; ++a)
    #pragma unroll
    for (int b = 0; b < 4; ++b)
      #pragma unroll
      for (int q = 0; q < 4; ++q) acc[a][b][q] = 0.f;
  const short* X = xnb + (size_t)n * 128 * 16384;
  for (int k0 = 0; k0 < 128; k0 += 32) {
    #pragma unroll
    for (int i2 = 0; i2 < 2; ++i2) {
      int u = t + 256 * i2;
      int row = u >> 2, kq = (u & 3) * 8;
      *(bf16x8*)&Asm[row * 40 + kq] = *(const bf16x8*)&w1b[(ob + row) * 128 + k0 + kq];
    }
    #pragma unroll
    for (int i2 = 0; i2 < 2; ++i2) {
      int u = t + 256 * i2;
      int k = u >> 4, p8 = (u & 15) * 8;
      bf16x8 hv = *(const bf16x8*)&X[(size_t)(k0 + k) * 16384 + pb + p8];
      #pragma unroll
      for (int j = 0; j < 8; ++j) Bsm[(p8 + j) * 40 + k] = hv[j];
    }
    __syncthreads();
    bf16x8 af[4], bfr[4];
    #pragma unroll
    for (int mf = 0; mf < 4; ++mf) af[mf] = *(bf16x8*)&Asm[(wm * 64 + mf * 16 + lr) * 40 + lk];
    #pragma unroll
    for (int nf = 0; nf < 4; ++nf) bfr[nf] = *(bf16x8*)&Bsm[(wn * 64 + nf * 16 + lr) * 40 + lk];
    #pragma unroll
    for (int mf = 0; mf < 4; ++mf)
      #pragma unroll
      for (int nf = 0; nf < 4; ++nf)
        acc[mf][nf] = MFMA16(af[mf], bfr[nf], acc[mf][nf]);
    __syncthreads();
  }
  #pragma unroll
  for (int mf = 0; mf < 4; ++mf)
    #pragma unroll
    for (int r = 0; r < 4; ++r) {
      int o = ob + wm * 64 + mf * 16 + (lane >> 4) * 4 + r;
      #pragma unroll
      for (int nf = 0; nf < 4; ++nf) {
        int p = pb + wn * 64 + nf * 16 + lr;
        h1[((size_t)(n * 512 + o)) * 16384 + p] = f2b(gelu_exact(acc[mf][nf][r]));
      }
    }
}

// ---------- MFMA GEMM 3: out = W2 . h1 + identity(y) ----------
__global__ __launch_bounds__(256) void k_mlp2_mfma(
    const short* __restrict__ h1, const short* __restrict__ w2b,
    const float* __restrict__ y, float* __restrict__ out) {
  const int pb = blockIdx.x * 128;
  const int ob = blockIdx.y * 128;
  const int n = blockIdx.z;
  __shared__ short Asm[128 * 40];
  __shared__ short Bsm[128 * 40];
  const int t = threadIdx.x;
  const int lane = t & 63, wv = t >> 6;
  const int wm = wv >> 1, wn = wv & 1;
  const int lr = lane & 15, lk = (lane >> 4) * 8;
  f32x4 acc[4][4];
  #pragma unroll
  for (int a = 0; a < 4; ++a)
    #pragma unroll
    for (int b = 0; b < 4; ++b)
      #pragma unroll
      for (int q = 0; q < 4; ++q) acc[a][b][q] = 0.f;
  const short* H = h1 + (size_t)n * 512 * 16384;
  for (int k0 = 0; k0 < 512; k0 += 32) {
    #pragma unroll
    for (int i2 = 0; i2 < 2; ++i2) {
      int u = t + 256 * i2;
      int row = u >> 2, kq = (u & 3) * 8;
      *(bf16x8*)&Asm[row * 40 + kq] = *(const bf16x8*)&w2b[(ob + row) * 512 + k0 + kq];
    }
    #pragma unroll
    for (int i2 = 0; i2 < 2; ++i2) {
      int u = t + 256 * i2;
      int k = u >> 4, p8 = (u & 15) * 8;
      bf16x8 hv = *(const bf16x8*)&H[(size_t)(k0 + k) * 16384 + pb + p8];
      #pragma unroll
      for (int j = 0; j < 8; ++j) Bsm[(p8 + j) * 40 + k] = hv[j];
    }
    __syncthreads();
    bf16x8 af[4], bfr[4];
    #pragma unroll
    for (int mf = 0; mf < 4; ++mf) af[mf] = *(bf16x8*)&Asm[(wm * 64 + mf * 16 + lr) * 40 + lk];
    #pragma unroll
    for (int nf = 0; nf < 4; ++nf) bfr[nf] = *(bf16x8*)&Bsm[(wn * 64 + nf * 16 + lr) * 40 + lk];
    #pragma unroll
    for (int mf = 0; mf < 4; ++mf)
      #pragma unroll
      for (int nf = 0; nf < 4; ++nf)
        acc[mf][nf] = MFMA16(af[mf], bfr[nf], acc[mf][nf]);
    __syncthreads();
  }
  #pragma unroll
  for (int mf = 0; mf < 4; ++mf)
    #pragma unroll
    for (int r = 0; r < 4; ++r) {
      int o = ob + wm * 64 + mf * 16 + (lane >> 4) * 4 + r;
      #pragma unroll
      for (int nf = 0; nf < 4; ++nf) {
        int p = pb + wn * 64 + nf * 16 + lr;
        size_t base = ((size_t)(n * 128 + o)) * 16384 + p;
        out[base] = acc[mf][nf][r] + y[base];
      }
    }
}

extern "C" void kernel_launch(void* const* d_in, const int* in_sizes, int n_in,
                              void* d_out, int out_size, void* d_ws, size_t ws_size,
                              hipStream_t stream) {
  const float* x        = (const float*)d_in[0];
  const float* w_qkv    = (const float*)d_in[1];
  const float* bn_qkv_g = (const float*)d_in[2];
  const float* bn_qkv_b = (const float*)d_in[3];
  const float* bn_sim_g = (const float*)d_in[4];
  const float* bn_sim_b = (const float*)d_in[5];
  const float* bn_out_g = (const float*)d_in[6];
  const float* bn_out_b = (const float*)d_in[7];
  const float* in_w     = (const float*)d_in[8];
  const float* in_b     = (const float*)d_in[9];
  const float* mlp_w1   = (const float*)d_in[10];
  const float* mlp_w2   = (const float*)d_in[11];
  const float* base_rel = (const float*)d_in[12];
  float* Wp = (float*)d_ws;

  float* relA   = Wp + 0;           // 135,424
  float* relAp  = Wp + 135424;      // 35,456
  float* relATp = Wp + 170880;      // 35,456
  __half* veA   = (__half*)(Wp + 206336);   // 67,584 dwords (16c x 33ap x 128i half2)
  float* qa     = Wp + 273920;      // 1,064,960
  float* ka     = Wp + 1338880;     // 1,064,960
  float* va     = Wp + 2403840;     // 2,129,920
  float* yb     = Wp + 4533760;     // 4,194,304
  short* xb     = (short*)(Wp + 8728064);   // 4,194,304 shorts
  short* xnb    = (short*)(Wp + 10825216);  // 4,194,304 shorts
  short* wqb    = (short*)(Wp + 12922368);  // 32,768 shorts
  short* w1b    = (short*)(Wp + 12938752);  // 65,536 shorts
  short* w2b    = (short*)(Wp + 12971520);  // 65,536 shorts
  short* qkvb   = (short*)(Wp + 13004288);  // 8,388,608 shorts (dead after k_down)
  short* h1b    = (short*)(Wp + 13004288);  // 16,777,216 shorts (overlays qkvb)
  // peak: 21,392,896 floats = 85.6 MB

  k_wbf<<<dim3(256), dim3(256), 0, stream>>>(w_qkv, mlp_w1, mlp_w2, wqb, w1b, w2b);
  k_xb<<<dim3(2048), dim3(256), 0, stream>>>(x, xb);
  k_relA<<<dim3(529), dim3(256), 0, stream>>>(base_rel, relA, relAp, relATp);
  k_vei<<<dim3(528), dim3(256), 0, stream>>>(relA, veA);
  k_qkv_mfma<<<dim3(2, 128, 2), dim3(256), 0, stream>>>(xb, wqb, bn_qkv_g, bn_qkv_b, qkvb);
  k_down<<<dim3(16640), dim3(256), 0, stream>>>(qkvb, qa, ka, va);
  k_attn<<<dim3(2048), dim3(256), 0, stream>>>(qa, ka, va, relAp, relATp, veA,
                                               bn_sim_g, bn_sim_b, bn_out_g, bn_out_b, yb);
  k_xn<<<dim3(256), dim3(256), 0, stream>>>(yb, in_w, in_b, xnb);
  k_mlp1_mfma<<<dim3(4, 128, 2), dim3(256), 0, stream>>>(xnb, w1b, h1b);
  k_mlp2_mfma<<<dim3(128, 1, 2), dim3(256), 0, stream>>>(h1b, w2b, yb, (float*)d_out);
}

// Round 7
// 198.617 us; speedup vs baseline: 1.3272x; 1.1258x over previous
//
#include <hip/hip_runtime.h>
#include <hip/hip_bf16.h>
#include <hip/hip_fp16.h>

#define GG 8
#define AA 65
#define BB 256

typedef __attribute__((ext_vector_type(8))) short bf16x8;
typedef __attribute__((ext_vector_type(4))) short s16x4;
typedef __attribute__((ext_vector_type(4))) float f32x4;
typedef _Float16 hf2 __attribute__((ext_vector_type(2)));
#define MFMA16(a, b, c) __builtin_amdgcn_mfma_f32_16x16x32_bf16(a, b, c, 0, 0, 0)

__device__ __forceinline__ void rz_taps(int o, float scale, int in_size,
                                        int& ia, int& ib, float& f) {
  float pos = (o + 0.5f) * scale - 0.5f;
  float fl = floorf(pos);
  int i0 = (int)fl;
  f = pos - fl;
  ia = i0 < 0 ? 0 : i0;
  int i1 = i0 + 1;
  ib = i1 > (in_size - 1) ? (in_size - 1) : i1;
}

// Compile-time 128->65 tap: pos = (j+0.5)*65/128-0.5 = (130j-63)/256 exactly.
#define JTAP(jc, ja, jb, fj) \
  const int num_ = 130 * (jc) - 63;               \
  const int fl_ = num_ >> 8;                      \
  const int ja = fl_ < 0 ? 0 : fl_;               \
  const int jb = (fl_ + 1 > 64) ? 64 : (fl_ + 1); \
  const float fj = (float)(num_ - (fl_ << 8)) * 0.00390625f;

__device__ __forceinline__ float gelu_exact(float v) {
  return 0.5f * v * (1.0f + erff(v * 0.70710678118654752f));
}

__device__ __forceinline__ short f2b(float f) {
  __hip_bfloat16 h = __float2bfloat16(f);
  return *reinterpret_cast<short*>(&h);
}
__device__ __forceinline__ float b2f(short s) {
  unsigned int u = ((unsigned int)(unsigned short)s) << 16;
  return __uint_as_float(u);
}

#define RSBN 0.99999500003749977f  // 1/sqrt(1+1e-5)

// ---------- W: weights -> bf16 ----------
__global__ void k_wbf(const float* __restrict__ wq, const float* __restrict__ w1,
                      const float* __restrict__ w2, short* __restrict__ wqb,
                      short* __restrict__ w1b, short* __restrict__ w2b) {
  int i = blockIdx.x * 256 + threadIdx.x;
  if (i < 32768) wqb[i] = f2b(wq[i]);
  if (i < 65536) { w1b[i] = f2b(w1[i]); w2b[i] = f2b(w2[i]); }
}

// ---------- A: base_relative -> relA (32,65,65) + padded q/k copies ----------
__global__ void k_relA(const float* __restrict__ base, float* __restrict__ relA,
                       float* __restrict__ relAp, float* __restrict__ relATp) {
  int idx = blockIdx.x * 256 + threadIdx.x;
  if (idx >= 32 * AA * AA) return;
  int j = idx % AA;
  int r = idx / AA;
  int i = r % AA;
  int c = r / AA;
  int ia, ib, ja, jb; float fi, fj;
  rz_taps(i, 255.0f / 65.0f, 255, ia, ib, fi);
  rz_taps(j, 255.0f / 65.0f, 255, ja, jb, fj);
  const float* S = base + (size_t)c * 255 * 255;
  float v = (1.0f - fi) * ((1.0f - fj) * S[ia * 255 + ja] + fj * S[ia * 255 + jb])
          + fi * ((1.0f - fj) * S[ib * 255 + ja] + fj * S[ib * 255 + jb]);
  relA[idx] = v;
  if (c < 8) relAp[c * 4420 + i * 68 + j] = v;
  else if (c < 16) relATp[(c - 8) * 4420 + j * 68 + i] = v;
}

// ---------- B: veA half2 layout: dword (c*33+ap)*128+i holds (a=2ap, a=2ap+1) ----------
__global__ void k_vei(const float* __restrict__ relA, __half* __restrict__ veA) {
  int idx = blockIdx.x * 256 + threadIdx.x;  // 16*66*128 = 135,168
  if (idx >= 16 * 66 * 128) return;
  int i = idx & 127;
  int r = idx >> 7;
  int a = r % 66, c = r / 66;
  float v = 0.f;
  if (a < 65) {
    int ia, ib; float fi;
    rz_taps(i, 65.0f / 128.0f, 65, ia, ib, fi);
    const float* S = relA + (size_t)(16 + c) * (AA * AA);
    v = (1.0f - fi) * S[ia * AA + a] + fi * S[ib * AA + a];
  }
  veA[((size_t)(c * 33 + (a >> 1)) * 128 + i) * 2 + (a & 1)] = __float2half(v);
}

// ---------- XA: downsample x along i (128->65) -> xab[n][a][c][w] bf16 ----------
__global__ void k_xa(const float* __restrict__ x, short* __restrict__ xab) {
  int idx = blockIdx.x * 256 + threadIdx.x;  // 2*65*128*128 = 2,129,920
  if (idx >= 2 * 65 * 128 * 128) return;
  int w = idx & 127;
  int c = (idx >> 7) & 127;
  int r = idx >> 14;            // n*65 + a
  int a = r % 65, n = r / 65;
  int ia, ib; float f;
  rz_taps(a, 128.0f / 65.0f, 128, ia, ib, f);
  const float* src = x + ((size_t)(n * 128 + c) * 128) * 128 + w;
  float v = (1.0f - f) * src[(size_t)ia * 128] + f * src[(size_t)ib * 128];
  xab[idx] = f2b(v);
}

// ---------- MFMA GEMM 1: qkva[n][o][a][w] = bf16(BN(Wqkv . xa)) ----------
__global__ __launch_bounds__(256) void k_qkv_mfma(
    const short* __restrict__ xab, const short* __restrict__ wqb,
    const float* __restrict__ bg, const float* __restrict__ bb,
    short* __restrict__ out) {
  const int ob = blockIdx.x * 128;
  const int a = blockIdx.y;
  const int n = blockIdx.z;
  __shared__ short Asm[128 * 40];
  __shared__ short Bsm[128 * 40];
  const int t = threadIdx.x;
  const int lane = t & 63, wv = t >> 6;
  const int wm = wv >> 1, wn = wv & 1;
  const int lr = lane & 15, lk = (lane >> 4) * 8;
  f32x4 acc[4][4];
  #pragma unroll
  for (int i = 0; i < 4; ++i)
    #pragma unroll
    for (int j = 0; j < 4; ++j)
      #pragma unroll
      for (int q = 0; q < 4; ++q) acc[i][j][q] = 0.f;
  const short* X = xab + (size_t)(n * 65 + a) * 128 * 128;  // [c][w]
  for (int k0 = 0; k0 < 128; k0 += 32) {
    #pragma unroll
    for (int i2 = 0; i2 < 2; ++i2) {
      int u = t + 256 * i2;
      int row = u >> 2, kq = (u & 3) * 8;
      *(bf16x8*)&Asm[row * 40 + kq] = *(const bf16x8*)&wqb[(ob + row) * 128 + k0 + kq];
    }
    #pragma unroll
    for (int i2 = 0; i2 < 2; ++i2) {
      int u = t + 256 * i2;
      int k = u >> 4, p8 = (u & 15) * 8;
      bf16x8 hv = *(const bf16x8*)&X[(k0 + k) * 128 + p8];
      #pragma unroll
      for (int j = 0; j < 8; ++j) Bsm[(p8 + j) * 40 + k] = hv[j];
    }
    __syncthreads();
    bf16x8 af[4], bfr[4];
    #pragma unroll
    for (int mf = 0; mf < 4; ++mf) af[mf] = *(bf16x8*)&Asm[(wm * 64 + mf * 16 + lr) * 40 + lk];
    #pragma unroll
    for (int nf = 0; nf < 4; ++nf) bfr[nf] = *(bf16x8*)&Bsm[(wn * 64 + nf * 16 + lr) * 40 + lk];
    #pragma unroll
    for (int mf = 0; mf < 4; ++mf)
      #pragma unroll
      for (int nf = 0; nf < 4; ++nf)
        acc[mf][nf] = MFMA16(af[mf], bfr[nf], acc[mf][nf]);
    __syncthreads();
  }
  #pragma unroll
  for (int mf = 0; mf < 4; ++mf) {
    #pragma unroll
    for (int r = 0; r < 4; ++r) {
      int o = ob + wm * 64 + mf * 16 + (lane >> 4) * 4 + r;
      float sc = bg[o] * RSBN, sh = bb[o];
      #pragma unroll
      for (int nf = 0; nf < 4; ++nf) {
        int p = wn * 64 + nf * 16 + lr;  // = w
        out[((size_t)(n * 256 + o) * 65 + a) * 128 + p] = f2b(acc[mf][nf][r] * sc + sh);
      }
    }
  }
}

// ---------- F: fused sim + softmax(register-T fold) + dot2 sv/sve + bn_out ----------
// Stages q/k/v directly from qkva (L2-served via XCD-chunked block swizzle).
__global__ void k_attn(const short* __restrict__ qkva, const float* __restrict__ relAp,
                       const float* __restrict__ relATp, const __half* __restrict__ veA,
                       const float* __restrict__ sg, const float* __restrict__ sb,
                       const float* __restrict__ og, const float* __restrict__ ob,
                       float* __restrict__ y) {
  int orig = blockIdx.x;
  int bg = ((orig & 7) << 8) + (orig >> 3);  // bijective XCD-chunk swizzle (2048 = 8*256)
  int b = bg >> 3, g = bg & 7;
  int n = b >> 7, w = b & 127;
  __shared__ float Ss[65 * 68];          // 17,680 B
  __shared__ __half PwsH[128 * 66];      // 16,896 B (66 = 33 a-pairs)
  __shared__ float u0[1088];             // qs(520)|ksp(544); vasH (16*66 halves) after
  __shared__ float Pinvs[128];
  float* qs = u0;
  float* ksp = u0 + 520;
  __half* vasH = (__half*)u0;
  int t = threadIdx.x;
  const short* Qbase = qkva + ((size_t)(n * 256 + g * 32) * 65) * 128 + w;

  // phase 1: stage q (ch 0..7) and k (ch 8..15) from qkva
  for (int l = t; l < 1040; l += 256) {
    int cc = l / 65, a = l - cc * 65;
    float v = b2f(Qbase[(size_t)l * 128]);
    if (cc < 8) qs[cc * 65 + a] = v;
    else ksp[(cc - 8) * 68 + a] = v;
  }
  __syncthreads();

  // phase 2: sim 65x65 (BN-combined qk+qr+kr), j-quad vectorized
  {
    float sqk = sg[g] * RSBN, sqr = sg[8 + g] * RSBN, skr = sg[16 + g] * RSBN;
    float badd = sb[g] + sb[8 + g] + sb[16 + g];
    for (int u = t; u < 65 * 17; u += 256) {
      int i = u / 17, jq = u - i * 17;
      float qv[8];
      #pragma unroll
      for (int c = 0; c < 8; ++c) qv[c] = qs[c * 65 + i];
      if (jq < 16) {
        int j0 = jq * 4;
        int lofs = i * 68 + j0;
        float qk0 = 0, qk1 = 0, qk2 = 0, qk3 = 0;
        float qr0 = 0, qr1 = 0, qr2 = 0, qr3 = 0;
        float kr0 = 0, kr1 = 0, kr2 = 0, kr3 = 0;
        #pragma unroll
        for (int c = 0; c < 8; ++c) {
          float4 kv = *(const float4*)&ksp[c * 68 + j0];
          float4 ra = *(const float4*)&relAp[c * 4420 + lofs];
          float4 rt = *(const float4*)&relATp[c * 4420 + lofs];
          float q = qv[c];
          qk0 += q * kv.x; qk1 += q * kv.y; qk2 += q * kv.z; qk3 += q * kv.w;
          qr0 += q * ra.x; qr1 += q * ra.y; qr2 += q * ra.z; qr3 += q * ra.w;
          kr0 += kv.x * rt.x; kr1 += kv.y * rt.y; kr2 += kv.z * rt.z; kr3 += kv.w * rt.w;
        }
        float4 res;
        res.x = sqk * qk0 + sqr * qr0 + skr * kr0 + badd;
        res.y = sqk * qk1 + sqr * qr1 + skr * kr1 + badd;
        res.z = sqk * qk2 + sqr * qr2 + skr * kr2 + badd;
        res.w = sqk * qk3 + sqr * qr3 + skr * kr3 + badd;
        *(float4*)&Ss[lofs] = res;
      } else {
        float qk = 0, qr = 0, kr = 0;
        int lofs = i * 68 + 64;
        #pragma unroll
        for (int c = 0; c < 8; ++c) {
          float kv = ksp[c * 68 + 64];
          qk += qv[c] * kv;
          qr += qv[c] * relAp[c * 4420 + lofs];
          kr += kv * relATp[c * 4420 + lofs];
        }
        Ss[lofs] = sqk * qk + sqr * qr + skr * kr + badd;
      }
    }
  }
  __syncthreads();

  // phase 3: v stage (fp16, a padded to 66, overlays u0) + register-T softmax fold
  for (int l = t; l < 16 * 66; l += 256) {
    int c = l / 66, a = l - c * 66;
    float v = (a < 65) ? b2f(Qbase[(size_t)((16 + c) * 65 + a) * 128]) : 0.f;
    vasH[l] = __float2half(v);
  }
  {
    const int i = t >> 1, h = t & 1;
    int ia, ib; float fi;
    rz_taps(i, 65.0f / 128.0f, 65, ia, ib, fi);
    const float* r0 = Ss + ia * 68 + h * 32;
    const float* r1 = Ss + ib * 68 + h * 32;
    const float wi0 = 1.0f - fi;
    float T[33];
    #pragma unroll
    for (int k = 0; k < 33; ++k) T[k] = wi0 * r0[k] + fi * r1[k];
    float mx = T[0];
    #pragma unroll
    for (int k = 1; k < 33; ++k) mx = fmaxf(mx, T[k]);
    mx = fmaxf(mx, __shfl_xor(mx, 1));
    float p[33];
    #pragma unroll
    for (int k = 0; k < 33; ++k) p[k] = 0.f;
    float sum = 0.f;
    if (h == 0) {
      #pragma unroll
      for (int j = 0; j < 64; ++j) {
        JTAP(j, ja, jb, fj);
        float v = (1.0f - fj) * T[ja] + fj * T[jb];
        float e = __expf(v - mx);
        sum += e;
        p[ja] += e * (1.0f - fj);
        p[jb] += e * fj;
      }
    } else {
      #pragma unroll
      for (int j = 64; j < 128; ++j) {
        JTAP(j, ja, jb, fj);
        float v = (1.0f - fj) * T[ja - 32] + fj * T[jb - 32];
        float e = __expf(v - mx);
        sum += e;
        p[ja - 32] += e * (1.0f - fj);
        p[jb - 32] += e * fj;
      }
    }
    sum += __shfl_xor(sum, 1);
    float other = __shfl_xor(h ? p[0] : p[32], 1);
    __half* prow = &PwsH[i * 66];
    if (h == 0) {
      p[32] += other;
      #pragma unroll
      for (int k = 0; k < 33; ++k) prow[k] = __float2half(p[k]);
      Pinvs[i] = 1.0f / sum;
    } else {
      p[0] += other;
      #pragma unroll
      for (int k = 0; k < 33; ++k) prow[32 + k] = __float2half(p[k]);
      prow[65] = __float2half(0.f);
    }
  }
  __syncthreads();

  // phase 4: dot2 contraction over 33 a-pairs; thread = (i, c-half)
  {
    const int i = t & 127;
    const int cg = t >> 7;
    const float inv = Pinvs[i];
    hf2 pw[33];
    const hf2* prow2 = (const hf2*)&PwsH[i * 66];
    #pragma unroll
    for (int ap = 0; ap < 33; ++ap) pw[ap] = prow2[ap];
    #pragma unroll
    for (int l = 0; l < 8; ++l) {
      const int c = cg * 8 + l;
      const hf2* vr = (const hf2*)&vasH[c * 66];
      const hf2* vp = (const hf2*)veA + (size_t)(c * 33) * 128 + i;
      float sv = 0.f, se = 0.f;
      #pragma unroll
      for (int ap = 0; ap < 33; ++ap) {
        sv = __builtin_amdgcn_fdot2(vr[ap], pw[ap], sv, false);
        se = __builtin_amdgcn_fdot2(vp[(size_t)ap * 128], pw[ap], se, false);
      }
      int c2 = g * 16 + c;
      int o0 = 2 * c2;
      float val = og[o0] * RSBN * (sv * inv) + ob[o0]
                + og[o0 + 1] * RSBN * (se * inv) + ob[o0 + 1];
      y[(((size_t)n * 128 + c2) * 128 + i) * 128 + w] = val;
    }
  }
}

// ---------- G: unified shift + instance-norm + bf16 write ----------
__global__ __launch_bounds__(256) void k_xn(const float* __restrict__ y,
                                            const float* __restrict__ inw,
                                            const float* __restrict__ inb,
                                            short* __restrict__ xnb) {
  int nc = blockIdx.x;
  int n = nc >> 7, cx = nc & 127;
  int sc_ch = cx, dh = 0, dw = 0;
  if (cx < 10)      { sc_ch = cx;      dw = -2; }
  else if (cx < 20) { sc_ch = cx - 10; dw = 2; }
  else if (cx < 30) { sc_ch = cx - 20; dh = -2; }
  else if (cx < 40) { sc_ch = cx - 30; dh = 2; }
  __shared__ short Sb[16384];
  __shared__ float sm[8];
  const float* src = y + ((size_t)n * 128 + sc_ch) * 16384;
  int t = threadIdx.x;
  #pragma unroll
  for (int l = 0; l < 16; ++l) {
    int q = t + l * 256;
    float4 v = *(const float4*)&src[q * 4];
    s16x4 o;
    o.x = f2b(v.x); o.y = f2b(v.y); o.z = f2b(v.z); o.w = f2b(v.w);
    *(s16x4*)&Sb[q * 4] = o;
  }
  __syncthreads();
  float s = 0.f, q2 = 0.f;
  for (int l = 0; l < 64; ++l) {
    int idx = t + l * 256;
    int h = idx >> 7, w = idx & 127;
    int hs = h + dh, ws = w + dw;
    float v = (hs >= 0 && hs < 128 && ws >= 0 && ws < 128) ? b2f(Sb[hs * 128 + ws]) : 0.f;
    s += v; q2 += v * v;
  }
  #pragma unroll
  for (int o = 32; o; o >>= 1) { s += __shfl_down(s, o); q2 += __shfl_down(q2, o); }
  if ((t & 63) == 0) { sm[(t >> 6) * 2] = s; sm[(t >> 6) * 2 + 1] = q2; }
  __syncthreads();
  float S_ = sm[0] + sm[2] + sm[4] + sm[6];
  float Q_ = sm[1] + sm[3] + sm[5] + sm[7];
  float mean = S_ * (1.0f / 16384.0f);
  float var = Q_ * (1.0f / 16384.0f) - mean * mean;
  float scale = inw[cx] * rsqrtf(var + 1e-5f);
  float shift = inb[cx] - mean * scale;
  short* dst = xnb + (size_t)nc * 16384;
  for (int l = 0; l < 64; ++l) {
    int idx = t + l * 256;
    int h = idx >> 7, w = idx & 127;
    int hs = h + dh, ws = w + dw;
    float v = (hs >= 0 && hs < 128 && ws >= 0 && ws < 128) ? b2f(Sb[hs * 128 + ws]) : 0.f;
    dst[idx] = f2b(v * scale + shift);
  }
}

// ---------- MFMA GEMM 2: h1 = gelu(W1 . xn), pure bf16 staging ----------
__global__ __launch_bounds__(256) void k_mlp1_mfma(
    const short* __restrict__ xnb, const short* __restrict__ w1b,
    short* __restrict__ h1) {
  const int ob = blockIdx.x * 128;
  const int pb = blockIdx.y * 128;
  const int n = blockIdx.z;
  __shared__ short Asm[128 * 40];
  __shared__ short Bsm[128 * 40];
  const int t = threadIdx.x;
  const int lane = t & 63, wv = t >> 6;
  const int wm = wv >> 1, wn = wv & 1;
  const int lr = lane & 15, lk = (lane >> 4) * 8;
  f32x4 acc[4][4];
  #pragma unroll
  for (int i = 0; i < 4; ++i)
    #pragma unroll
    for (int j = 0; j < 4; ++j)
      #pragma unroll
      for (int q = 0; q < 4; ++q) acc[i][j][q] = 0.f;
  const short* X = xnb + (size_t)n * 128 * 16384;
  for (int k0 = 0; k0 < 128; k0 += 32) {
    #pragma unroll
    for (int i2 = 0; i2 < 2; ++i2) {
      int u = t + 256 * i2;
      int row = u >> 2, kq = (u & 3) * 8;
      *(bf16x8*)&Asm[row * 40 + kq] = *(const bf16x8*)&w1b[(ob + row) * 128 + k0 + kq];
    }
    #pragma unroll
    for (int i2 = 0; i2 < 2; ++i2) {
      int u = t + 256 * i2;
      int k = u >> 4, p8 = (u & 15) * 8;
      bf16x8 hv = *(const bf16x8*)&X[(size_t)(k0 + k) * 16384 + pb + p8];
      #pragma unroll
      for (int j = 0; j < 8; ++j) Bsm[(p8 + j) * 40 + k] = hv[j];
    }
    __syncthreads();
    bf16x8 af[4], bfr[4];
    #pragma unroll
    for (int mf = 0; mf < 4; ++mf) af[mf] = *(bf16x8*)&Asm[(wm * 64 + mf * 16 + lr) * 40 + lk];
    #pragma unroll
    for (int nf = 0; nf < 4; ++nf) bfr[nf] = *(bf16x8*)&Bsm[(wn * 64 + nf * 16 + lr) * 40 + lk];
    #pragma unroll
    for (int mf = 0; mf < 4; ++mf)
      #pragma unroll
      for (int nf = 0; nf < 4; ++nf)
        acc[mf][nf] = MFMA16(af[mf], bfr[nf], acc[mf][nf]);
    __syncthreads();
  }
  #pragma unroll
  for (int mf = 0; mf < 4; ++mf)
    #pragma unroll
    for (int r = 0; r < 4; ++r) {
      int o = ob + wm * 64 + mf * 16 + (lane >> 4) * 4 + r;
      #pragma unroll
      for (int nf = 0; nf < 4; ++nf) {
        int p = pb + wn * 64 + nf * 16 + lr;
        h1[((size_t)(n * 512 + o)) * 16384 + p] = f2b(gelu_exact(acc[mf][nf][r]));
      }
    }
}

// ---------- MFMA GEMM 3: out = W2 . h1 + identity(y) ----------
__global__ __launch_bounds__(256) void k_mlp2_mfma(
    const short* __restrict__ h1, const short* __restrict__ w2b,
    const float* __restrict__ y, float* __restrict__ out) {
  const int pb = blockIdx.x * 128;
  const int ob = blockIdx.y * 128;
  const int n = blockIdx.z;
  __shared__ short Asm[128 * 40];
  __shared__ short Bsm[128 * 40];
  const int t = threadIdx.x;
  const int lane = t & 63, wv = t >> 6;
  const int wm = wv >> 1, wn = wv & 1;
  const int lr = lane & 15, lk = (lane >> 4) * 8;
  f32x4 acc[4][4];
  #pragma unroll
  for (int i = 0; i < 4; ++i)
    #pragma unroll
    for (int j = 0; j < 4; ++j)
      #pragma unroll
      for (int q = 0; q < 4; ++q) acc[i][j][q] = 0.f;
  const short* H = h1 + (size_t)n * 512 * 16384;
  for (int k0 = 0; k0 < 512; k0 += 32) {
    #pragma unroll
    for (int i2 = 0; i2 < 2; ++i2) {
      int u = t + 256 * i2;
      int row = u >> 2, kq = (u & 3) * 8;
      *(bf16x8*)&Asm[row * 40 + kq] = *(const bf16x8*)&w2b[(ob + row) * 512 + k0 + kq];
    }
    #pragma unroll
    for (int i2 = 0; i2 < 2; ++i2) {
      int u = t + 256 * i2;
      int k = u >> 4, p8 = (u & 15) * 8;
      bf16x8 hv = *(const bf16x8*)&H[(size_t)(k0 + k) * 16384 + pb + p8];
      #pragma unroll
      for (int j = 0; j < 8; ++j) Bsm[(p8 + j) * 40 + k] = hv[j];
    }
    __syncthreads();
    bf16x8 af[4], bfr[4];
    #pragma unroll
    for (int mf = 0; mf < 4; ++mf) af[mf] = *(bf16x8*)&Asm[(wm * 64 + mf * 16 + lr) * 40 + lk];
    #pragma unroll
    for (int nf = 0; nf < 4; ++nf) bfr[nf] = *(bf16x8*)&Bsm[(wn * 64 + nf * 16 + lr) * 40 + lk];
    #pragma unroll
    for (int mf = 0; mf < 4; ++mf)
      #pragma unroll
      for (int nf = 0; nf < 4; ++nf)
        acc[mf][nf] = MFMA16(af[mf], bfr[nf], acc[mf][nf]);
    __syncthreads();
  }
  #pragma unroll
  for (int mf = 0; mf < 4; ++mf)
    #pragma unroll
    for (int r = 0; r < 4; ++r) {
      int o = ob + wm * 64 + mf * 16 + (lane >> 4) * 4 + r;
      #pragma unroll
      for (int nf = 0; nf < 4; ++nf) {
        int p = pb + wn * 64 + nf * 16 + lr;
        size_t base = ((size_t)(n * 128 + o)) * 16384 + p;
        out[base] = acc[mf][nf][r] + y[base];
      }
    }
}

extern "C" void kernel_launch(void* const* d_in, const int* in_sizes, int n_in,
                              void* d_out, int out_size, void* d_ws, size_t ws_size,
                              hipStream_t stream) {
  const float* x        = (const float*)d_in[0];
  const float* w_qkv    = (const float*)d_in[1];
  const float* bn_qkv_g = (const float*)d_in[2];
  const float* bn_qkv_b = (const float*)d_in[3];
  const float* bn_sim_g = (const float*)d_in[4];
  const float* bn_sim_b = (const float*)d_in[5];
  const float* bn_out_g = (const float*)d_in[6];
  const float* bn_out_b = (const float*)d_in[7];
  const float* in_w     = (const float*)d_in[8];
  const float* in_b     = (const float*)d_in[9];
  const float* mlp_w1   = (const float*)d_in[10];
  const float* mlp_w2   = (const float*)d_in[11];
  const float* base_rel = (const float*)d_in[12];
  float* Wp = (float*)d_ws;

  float* relA   = Wp + 0;           // 135,424
  float* relAp  = Wp + 135424;      // 35,456
  float* relATp = Wp + 170880;      // 35,456
  __half* veA   = (__half*)(Wp + 206336);   // 67,584 f (135,168 halves)
  float* yb     = Wp + 273920;      // 4,194,304
  short* wqb    = (short*)(Wp + 4468224);   // 32,768 shorts
  short* w1b    = (short*)(Wp + 4484608);   // 65,536 shorts
  short* w2b    = (short*)(Wp + 4517376);   // 65,536 shorts
  short* xnb    = (short*)(Wp + 4550144);   // 4,194,304 shorts (2,097,152 f)
  short* xab    = (short*)(Wp + 6647296);   // 2,129,920 shorts (dead after qkv)
  short* qkva   = (short*)(Wp + 7712256);   // 4,259,840 shorts (dead after attn)
  short* h1b    = (short*)(Wp + 6647296);   // 16,777,216 shorts (overlays xab+qkva)
  // peak: 15,035,904 floats = 60.1 MB

  k_wbf<<<dim3(256), dim3(256), 0, stream>>>(w_qkv, mlp_w1, mlp_w2, wqb, w1b, w2b);
  k_relA<<<dim3(529), dim3(256), 0, stream>>>(base_rel, relA, relAp, relATp);
  k_vei<<<dim3(528), dim3(256), 0, stream>>>(relA, veA);
  k_xa<<<dim3(8320), dim3(256), 0, stream>>>(x, xab);
  k_qkv_mfma<<<dim3(2, 65, 2), dim3(256), 0, stream>>>(xab, wqb, bn_qkv_g, bn_qkv_b, qkva);
  k_attn<<<dim3(2048), dim3(256), 0, stream>>>(qkva, relAp, relATp, veA,
                                               bn_sim_g, bn_sim_b, bn_out_g, bn_out_b, yb);
  k_xn<<<dim3(256), dim3(256), 0, stream>>>(yb, in_w, in_b, xnb);
  k_mlp1_mfma<<<dim3(4, 128, 2), dim3(256), 0, stream>>>(xnb, w1b, h1b);
  k_mlp2_mfma<<<dim3(128, 1, 2), dim3(256), 0, stream>>>(h1b, w2b, yb, (float*)d_out);
}